// Round 1
// baseline (439.685 us; speedup 1.0000x reference)
//
#include <hip/hip_runtime.h>
#include <math.h>

// AdaptiveAttention: O = softmax(sigmoid(span)_k * (Q K^T)/sqrt(D)) V
// B=4, Sq=Sk=D=2048, fp32 in/out.
//
// Strategy: bf16 MFMA two-pass.
//   ws layout (needs ~134.3 MB):
//     [0)          Qb  bf16  33.55 MB
//     [TEN*2)      Kb  bf16  33.55 MB
//     [TEN*4)      Vt  bf16  33.55 MB   (V transposed per batch: [d][k])
//     [TEN*6)      E   bf16  33.55 MB   (exp(scale*g*QK^T), unnormalized)
//     [TEN*8)      Z   f32   32 KB      (row sums)
//   K1: E = exp(scale * sigmoid(span[k]) * Q.K^T), Z[q] += row sums (atomics)
//   K2: O = (E . Vt^T) / Z[q]
// Both GEMMs: 128x128 tile, BK=64, 4 waves (2x2 of 64x64), mfma_16x16x32_bf16,
// global_load_lds width-16 staging (m97 structure).

#define SEQ 2048
#define HID 2048
#define NB 4

typedef __attribute__((ext_vector_type(8))) __bf16 bf16x8;
typedef __attribute__((ext_vector_type(4))) float f32x4;
typedef __attribute__((ext_vector_type(8))) unsigned short ushort8;

#define GLD16(src, dst)                                              \
  __builtin_amdgcn_global_load_lds(                                  \
      (const __attribute__((address_space(1))) void*)(src),          \
      (__attribute__((address_space(3))) void*)(dst), 16, 0, 0)

__device__ __forceinline__ unsigned short f2bf(float f) {
  unsigned u = __float_as_uint(f);
  u += 0x7fffu + ((u >> 16) & 1u);  // RNE
  return (unsigned short)(u >> 16);
}

// ---------------- fp32 -> bf16 elementwise ----------------
__global__ __launch_bounds__(256) void cvt_kernel(
    const float* __restrict__ in, unsigned short* __restrict__ out, int n) {
  size_t stride = (size_t)gridDim.x * blockDim.x * 8;
  for (size_t i = ((size_t)blockIdx.x * blockDim.x + threadIdx.x) * 8;
       i < (size_t)n; i += stride) {
    float4 v0 = *reinterpret_cast<const float4*>(in + i);
    float4 v1 = *reinterpret_cast<const float4*>(in + i + 4);
    ushort8 o;
    o[0] = f2bf(v0.x); o[1] = f2bf(v0.y); o[2] = f2bf(v0.z); o[3] = f2bf(v0.w);
    o[4] = f2bf(v1.x); o[5] = f2bf(v1.y); o[6] = f2bf(v1.z); o[7] = f2bf(v1.w);
    *reinterpret_cast<ushort8*>(out + i) = o;
  }
}

// ---------------- V [b][k][d] fp32 -> Vt [b][d][k] bf16 ----------------
__global__ __launch_bounds__(256) void tcvt_kernel(
    const float* __restrict__ V, unsigned short* __restrict__ Vt) {
  __shared__ unsigned short tile[64][65];
  int b = blockIdx.z;
  int k0 = blockIdx.x * 64;
  int d0 = blockIdx.y * 64;
  const float* src = V + ((size_t)b * SEQ + k0) * HID + d0;
  unsigned short* dst = Vt + ((size_t)b * HID + d0) * SEQ + k0;
  int t = threadIdx.x;
#pragma unroll
  for (int i = 0; i < 4; ++i) {
    int j = i * 256 + t;
    int r = j >> 4;         // k-local 0..63
    int c = (j & 15) * 4;   // d-local
    float4 v = *reinterpret_cast<const float4*>(src + (size_t)r * HID + c);
    tile[c + 0][r] = f2bf(v.x);
    tile[c + 1][r] = f2bf(v.y);
    tile[c + 2][r] = f2bf(v.z);
    tile[c + 3][r] = f2bf(v.w);
  }
  __syncthreads();
#pragma unroll
  for (int i = 0; i < 2; ++i) {
    int j = i * 256 + t;
    int r = j >> 3;        // d-local 0..63
    int c = (j & 7) * 8;   // k-local
    ushort8 o;
#pragma unroll
    for (int e = 0; e < 8; ++e) o[e] = tile[r][c + e];
    *reinterpret_cast<ushort8*>(dst + (size_t)r * SEQ + c) = o;
  }
}

// ---------------- GEMM1: E = exp(scale * g[k] * Q.K^T), Z += rowsums -------
__global__ __launch_bounds__(256) void gemm1_kernel(
    const unsigned short* __restrict__ Q, const unsigned short* __restrict__ K,
    unsigned short* __restrict__ E, float* __restrict__ Z,
    const float* __restrict__ span) {
  __shared__ __align__(16) unsigned short Asm[128 * 64];
  __shared__ __align__(16) unsigned short Bsm[128 * 64];
  int bid = blockIdx.x;
  int swz = (bid & 7) * ((int)gridDim.x >> 3) + (bid >> 3);  // XCD swizzle
  int b = swz >> 8;
  int tl = swz & 255;
  int brow = tl >> 4, bcol = tl & 15;
  const unsigned short* A = Q + (size_t)b * SEQ * HID + (size_t)brow * 128 * HID;
  const unsigned short* B = K + (size_t)b * SEQ * HID + (size_t)bcol * 128 * HID;
  unsigned short* Eb = E + (size_t)b * SEQ * SEQ;
  float* Zb = Z + b * SEQ;

  int tid = threadIdx.x;
  int l = tid & 63, w = tid >> 6;
  const unsigned short* agA[4];
  const unsigned short* agB[4];
  int ldsOfs[4];
#pragma unroll
  for (int i = 0; i < 4; ++i) {
    int j = i * 256 + tid;
    int row = j >> 3, kc = (j & 7) * 8;
    agA[i] = A + (size_t)row * HID + kc;
    agB[i] = B + (size_t)row * HID + kc;
    ldsOfs[i] = (i * 256 + w * 64) * 8;  // wave-uniform LDS base (elements)
  }
  f32x4 acc[4][4];
#pragma unroll
  for (int m = 0; m < 4; ++m)
#pragma unroll
    for (int n = 0; n < 4; ++n) acc[m][n] = (f32x4){0.f, 0.f, 0.f, 0.f};

  int wr = w >> 1, wc = w & 1;
  int lr = l & 15, lh = l >> 4;

  for (int kt = 0; kt < HID / 64; ++kt) {
    if (kt) __syncthreads();
#pragma unroll
    for (int i = 0; i < 4; ++i) GLD16(agA[i] + kt * 64, Asm + ldsOfs[i]);
#pragma unroll
    for (int i = 0; i < 4; ++i) GLD16(agB[i] + kt * 64, Bsm + ldsOfs[i]);
    __syncthreads();
#pragma unroll
    for (int kk = 0; kk < 2; ++kk) {
      bf16x8 af[4], bfr[4];
#pragma unroll
      for (int m = 0; m < 4; ++m)
        af[m] = *reinterpret_cast<const bf16x8*>(
            &Asm[(wr * 64 + m * 16 + lr) * 64 + kk * 32 + lh * 8]);
#pragma unroll
      for (int n = 0; n < 4; ++n)
        bfr[n] = *reinterpret_cast<const bf16x8*>(
            &Bsm[(wc * 64 + n * 16 + lr) * 64 + kk * 32 + lh * 8]);
#pragma unroll
      for (int m = 0; m < 4; ++m)
#pragma unroll
        for (int n = 0; n < 4; ++n)
          acc[m][n] =
              __builtin_amdgcn_mfma_f32_16x16x32_bf16(af[m], bfr[n], acc[m][n], 0, 0, 0);
    }
  }

  const float scale = 0.02209708691207961f;  // 1/sqrt(2048)
  float g[4];
  int coln[4];
#pragma unroll
  for (int n = 0; n < 4; ++n) {
    int col = bcol * 128 + wc * 64 + n * 16 + lr;
    coln[n] = col;
    g[n] = scale / (1.0f + __expf(-span[col]));  // scale * sigmoid(span[k])
  }
#pragma unroll
  for (int m = 0; m < 4; ++m) {
    int rbase = brow * 128 + wr * 64 + m * 16 + lh * 4;
#pragma unroll
    for (int j = 0; j < 4; ++j) {
      int q = rbase + j;
      float rs = 0.f;
#pragma unroll
      for (int n = 0; n < 4; ++n) {
        float e = __expf(acc[m][n][j] * g[n]);
        Eb[(size_t)q * SEQ + coln[n]] = f2bf(e);
        rs += e;
      }
      rs += __shfl_xor(rs, 1, 16);
      rs += __shfl_xor(rs, 2, 16);
      rs += __shfl_xor(rs, 4, 16);
      rs += __shfl_xor(rs, 8, 16);
      if (lr == 0) atomicAdd(&Zb[q], rs);
    }
  }
}

// ---------------- GEMM2: O = (E . Vt^T) / Z[q] ----------------
__global__ __launch_bounds__(256) void gemm2_kernel(
    const unsigned short* __restrict__ E, const unsigned short* __restrict__ Vt,
    float* __restrict__ Out, const float* __restrict__ Z) {
  __shared__ __align__(16) unsigned short Asm[128 * 64];
  __shared__ __align__(16) unsigned short Bsm[128 * 64];
  int bid = blockIdx.x;
  int swz = (bid & 7) * ((int)gridDim.x >> 3) + (bid >> 3);
  int b = swz >> 8;
  int tl = swz & 255;
  int brow = tl >> 4, bcol = tl & 15;
  const unsigned short* A = E + (size_t)b * SEQ * SEQ + (size_t)brow * 128 * SEQ;
  const unsigned short* B = Vt + (size_t)b * HID * SEQ + (size_t)bcol * 128 * SEQ;
  float* Outb = Out + (size_t)b * SEQ * HID;
  const float* Zb = Z + b * SEQ;

  int tid = threadIdx.x;
  int l = tid & 63, w = tid >> 6;
  const unsigned short* agA[4];
  const unsigned short* agB[4];
  int ldsOfs[4];
#pragma unroll
  for (int i = 0; i < 4; ++i) {
    int j = i * 256 + tid;
    int row = j >> 3, kc = (j & 7) * 8;
    agA[i] = A + (size_t)row * SEQ + kc;
    agB[i] = B + (size_t)row * SEQ + kc;
    ldsOfs[i] = (i * 256 + w * 64) * 8;
  }
  f32x4 acc[4][4];
#pragma unroll
  for (int m = 0; m < 4; ++m)
#pragma unroll
    for (int n = 0; n < 4; ++n) acc[m][n] = (f32x4){0.f, 0.f, 0.f, 0.f};

  int wr = w >> 1, wc = w & 1;
  int lr = l & 15, lh = l >> 4;

  for (int kt = 0; kt < SEQ / 64; ++kt) {
    if (kt) __syncthreads();
#pragma unroll
    for (int i = 0; i < 4; ++i) GLD16(agA[i] + kt * 64, Asm + ldsOfs[i]);
#pragma unroll
    for (int i = 0; i < 4; ++i) GLD16(agB[i] + kt * 64, Bsm + ldsOfs[i]);
    __syncthreads();
#pragma unroll
    for (int kk = 0; kk < 2; ++kk) {
      bf16x8 af[4], bfr[4];
#pragma unroll
      for (int m = 0; m < 4; ++m)
        af[m] = *reinterpret_cast<const bf16x8*>(
            &Asm[(wr * 64 + m * 16 + lr) * 64 + kk * 32 + lh * 8]);
#pragma unroll
      for (int n = 0; n < 4; ++n)
        bfr[n] = *reinterpret_cast<const bf16x8*>(
            &Bsm[(wc * 64 + n * 16 + lr) * 64 + kk * 32 + lh * 8]);
#pragma unroll
      for (int m = 0; m < 4; ++m)
#pragma unroll
        for (int n = 0; n < 4; ++n)
          acc[m][n] =
              __builtin_amdgcn_mfma_f32_16x16x32_bf16(af[m], bfr[n], acc[m][n], 0, 0, 0);
    }
  }

#pragma unroll
  for (int m = 0; m < 4; ++m) {
    int rbase = brow * 128 + wr * 64 + m * 16 + lh * 4;
#pragma unroll
    for (int j = 0; j < 4; ++j) {
      int q = rbase + j;
      float zi = 1.0f / Zb[q];
#pragma unroll
      for (int n = 0; n < 4; ++n) {
        int col = bcol * 128 + wc * 64 + n * 16 + lr;
        Outb[(size_t)q * HID + col] = acc[m][n][j] * zi;
      }
    }
  }
}

extern "C" void kernel_launch(void* const* d_in, const int* in_sizes, int n_in,
                              void* d_out, int out_size, void* d_ws, size_t ws_size,
                              hipStream_t stream) {
  const float* Q = (const float*)d_in[0];
  const float* K = (const float*)d_in[1];
  const float* V = (const float*)d_in[2];
  const float* span = (const float*)d_in[3];
  float* out = (float*)d_out;
  char* ws = (char*)d_ws;

  const size_t TEN = (size_t)NB * SEQ * HID;  // 16,777,216 elements per tensor
  unsigned short* Qb = (unsigned short*)(ws);
  unsigned short* Kb = (unsigned short*)(ws + TEN * 2);
  unsigned short* Vt = (unsigned short*)(ws + TEN * 4);
  unsigned short* E  = (unsigned short*)(ws + TEN * 6);
  float* Z = (float*)(ws + TEN * 8);  // total need: TEN*8 + 32KB ~= 134.3 MB

  hipMemsetAsync(Z, 0, (size_t)NB * SEQ * sizeof(float), stream);
  cvt_kernel<<<4096, 256, 0, stream>>>(Q, Qb, (int)TEN);
  cvt_kernel<<<4096, 256, 0, stream>>>(K, Kb, (int)TEN);
  tcvt_kernel<<<dim3(SEQ / 64, HID / 64, NB), 256, 0, stream>>>(V, Vt);
  gemm1_kernel<<<1024, 256, 0, stream>>>(Qb, Kb, E, Z, span);
  gemm2_kernel<<<1024, 256, 0, stream>>>(E, Vt, out, Z);
}

// Round 2
// 355.071 us; speedup vs baseline: 1.2383x; 1.2383x over previous
//
#include <hip/hip_runtime.h>
#include <math.h>

// AdaptiveAttention: O = softmax(sigmoid(span)_k * (Q K^T)/sqrt(D)) V
// B=4, Sq=Sk=D=2048, fp32 in/out.
//
// ws layout (~134.3 MB):
//   [0)      Qb bf16   [TEN*2) Kb bf16   [TEN*4) Vt bf16 ([b][d][k])
//   [TEN*6)  E  bf16   [TEN*8) Z  f32 (32 KB row sums)
// K1: E = exp(scale*sigmoid(span[k]) * Q.K^T), Z[q] += rowsums (atomic)
// K2: O = (E . Vt^T) / Z[q]
//
// GEMM structure (T3+T4+T2+T5): 256x256 tile, BK=32, 8 waves (2Mx4N),
// 4-deep LDS ring (128 KiB), 3 K-tiles in flight, counted vmcnt(8),
// raw s_barrier phases, XOR slot swizzle (2-way max bank aliasing),
// setprio around MFMA clusters, bijective XCD blockIdx swizzle.

#define SEQ 2048
#define HID 2048
#define NB 4
#define S 2048  // lda/ldb/ldc for both gemms (SEQ==HID)

typedef __attribute__((ext_vector_type(8))) __bf16 bf16x8;
typedef __attribute__((ext_vector_type(4))) float f32x4;
typedef __attribute__((ext_vector_type(8))) unsigned short ushort8;

#define GLD16(src, dst)                                              \
  __builtin_amdgcn_global_load_lds(                                  \
      (const __attribute__((address_space(1))) void*)(src),          \
      (__attribute__((address_space(3))) void*)(dst), 16, 0, 0)

__device__ __forceinline__ unsigned short f2bf(float f) {
  unsigned u = __float_as_uint(f);
  u += 0x7fffu + ((u >> 16) & 1u);  // RNE
  return (unsigned short)(u >> 16);
}

// ---------------- fp32 -> bf16 elementwise (Q and K in one launch) --------
__global__ __launch_bounds__(256) void cvt2_kernel(
    const float* __restrict__ q, const float* __restrict__ k,
    unsigned short* __restrict__ qb, unsigned short* __restrict__ kb) {
  const size_t n = (size_t)NB * SEQ * HID;
  int half = gridDim.x >> 1;
  const float* in;
  unsigned short* out;
  int bx = blockIdx.x;
  if (bx < half) { in = q; out = qb; } else { in = k; out = kb; bx -= half; }
  size_t stride = (size_t)half * blockDim.x * 8;
  for (size_t i = ((size_t)bx * blockDim.x + threadIdx.x) * 8; i < n; i += stride) {
    float4 v0 = *reinterpret_cast<const float4*>(in + i);
    float4 v1 = *reinterpret_cast<const float4*>(in + i + 4);
    ushort8 o;
    o[0] = f2bf(v0.x); o[1] = f2bf(v0.y); o[2] = f2bf(v0.z); o[3] = f2bf(v0.w);
    o[4] = f2bf(v1.x); o[5] = f2bf(v1.y); o[6] = f2bf(v1.z); o[7] = f2bf(v1.w);
    *reinterpret_cast<ushort8*>(out + i) = o;
  }
}

// ---------------- V [b][k][d] fp32 -> Vt [b][d][k] bf16 ----------------
__global__ __launch_bounds__(256) void tcvt_kernel(
    const float* __restrict__ V, unsigned short* __restrict__ Vt) {
  __shared__ unsigned short tile[64][65];
  int b = blockIdx.z;
  int k0 = blockIdx.x * 64;
  int d0 = blockIdx.y * 64;
  const float* src = V + ((size_t)b * SEQ + k0) * HID + d0;
  unsigned short* dst = Vt + ((size_t)b * HID + d0) * SEQ + k0;
  int t = threadIdx.x;
#pragma unroll
  for (int i = 0; i < 4; ++i) {
    int j = i * 256 + t;
    int r = j >> 4;
    int c = (j & 15) * 4;
    float4 v = *reinterpret_cast<const float4*>(src + (size_t)r * HID + c);
    tile[c + 0][r] = f2bf(v.x);
    tile[c + 1][r] = f2bf(v.y);
    tile[c + 2][r] = f2bf(v.z);
    tile[c + 3][r] = f2bf(v.w);
  }
  __syncthreads();
#pragma unroll
  for (int i = 0; i < 2; ++i) {
    int j = i * 256 + t;
    int r = j >> 3;
    int c = (j & 7) * 8;
    ushort8 o;
#pragma unroll
    for (int e = 0; e < 8; ++e) o[e] = tile[r][c + e];
    *reinterpret_cast<ushort8*>(dst + (size_t)r * SEQ + c) = o;
  }
}

// ---------------- 256^2-tile deep-pipelined NT GEMM ----------------
// C[M,N] = A[M,K] . B[N,K]^T per batch, M=N=K=2048, bf16 in, f32 acc.
// IS_G1: epilogue exp+rowsum->E,Z.  else: epilogue /Z -> f32 out.

#define K_ITER(VMC, DOSTAGE)                                                  \
  {                                                                           \
    asm volatile("s_waitcnt vmcnt(" #VMC ")" ::: "memory");                   \
    __builtin_amdgcn_s_barrier();                                             \
    asm volatile("" ::: "memory");                                            \
    int lb = (t & 3) * 16384;                                                 \
    bf16x8 af[8], bfr[4];                                                     \
    _Pragma("unroll")                                                         \
    for (int m = 0; m < 4; ++m)                                               \
      af[m] = *(const bf16x8*)&lds[lb + aOff[m]];                             \
    _Pragma("unroll")                                                         \
    for (int n = 0; n < 4; ++n)                                               \
      bfr[n] = *(const bf16x8*)&lds[lb + bOff[n]];                            \
    if (DOSTAGE) {                                                            \
      int sb = ((t + 3) & 3) * 16384;                                         \
      GLD16(aS0 + (size_t)(t + 3) * 32, &lds[sb + ldsA0]);                    \
      GLD16(aS1 + (size_t)(t + 3) * 32, &lds[sb + ldsA1]);                    \
    }                                                                         \
    __builtin_amdgcn_s_barrier();                                             \
    asm volatile("s_waitcnt lgkmcnt(0)" ::: "memory");                        \
    __builtin_amdgcn_s_setprio(1);                                            \
    _Pragma("unroll")                                                         \
    for (int m = 0; m < 4; ++m)                                               \
      _Pragma("unroll")                                                       \
      for (int n = 0; n < 4; ++n)                                             \
        acc[m][n] = __builtin_amdgcn_mfma_f32_16x16x32_bf16(af[m], bfr[n],    \
                                                            acc[m][n], 0, 0, 0); \
    __builtin_amdgcn_s_setprio(0);                                            \
    __builtin_amdgcn_s_barrier();                                             \
    asm volatile("" ::: "memory");                                            \
    _Pragma("unroll")                                                         \
    for (int m = 4; m < 8; ++m)                                               \
      af[m] = *(const bf16x8*)&lds[lb + aOff[m]];                             \
    if (DOSTAGE) {                                                            \
      int sb = ((t + 3) & 3) * 16384;                                         \
      GLD16(bS0 + (size_t)(t + 3) * 32, &lds[sb + ldsB0]);                    \
      GLD16(bS1 + (size_t)(t + 3) * 32, &lds[sb + ldsB1]);                    \
    }                                                                         \
    asm volatile("s_waitcnt lgkmcnt(0)" ::: "memory");                        \
    __builtin_amdgcn_s_setprio(1);                                            \
    _Pragma("unroll")                                                         \
    for (int m = 4; m < 8; ++m)                                               \
      _Pragma("unroll")                                                       \
      for (int n = 0; n < 4; ++n)                                             \
        acc[m][n] = __builtin_amdgcn_mfma_f32_16x16x32_bf16(af[m], bfr[n],    \
                                                            acc[m][n], 0, 0, 0); \
    __builtin_amdgcn_s_setprio(0);                                            \
  }

template <bool IS_G1>
__global__ __launch_bounds__(512, 2) void gemm_kernel(
    const unsigned short* __restrict__ Amat, const unsigned short* __restrict__ Bmat,
    void* __restrict__ outp, float* __restrict__ Z, const float* __restrict__ span) {
  __shared__ __align__(16) unsigned short lds[4 * 16384];  // 128 KiB ring

  int bid = blockIdx.x;
  int swz = (bid & 7) * 32 + (bid >> 3);  // 256 blocks, bijective XCD swizzle
  int b = swz >> 6;
  int tile = swz & 63;
  int brow = tile >> 3, bcol = tile & 7;
  const unsigned short* A = Amat + (size_t)b * S * S + (size_t)brow * 256 * S;
  const unsigned short* B = Bmat + (size_t)b * S * S + (size_t)bcol * 256 * S;

  int tid = threadIdx.x;
  int w = tid >> 6, l = tid & 63;
  int wr = w >> 2, wc = w & 3;
  int lr = l & 15, lh = l >> 4;

  // --- staging: per wave 4 x global_load_lds per K-tile (A half rows
  // [w*16, +16) and +128; same for B). Linear LDS dest; global source
  // pre-swizzled so reads can use slot ^= (row>>1)&3.
  int srcSwz = ((l & 3) ^ ((l >> 3) & 3)) * 8;
  const unsigned short* aS0 = A + (size_t)(w * 16 + (l >> 2)) * S + srcSwz;
  const unsigned short* aS1 = aS0 + (size_t)128 * S;
  const unsigned short* bS0 = B + (size_t)(w * 16 + (l >> 2)) * S + srcSwz;
  const unsigned short* bS1 = bS0 + (size_t)128 * S;
  int ldsA0 = w * 512;            // (w*16)*32
  int ldsA1 = w * 512 + 4096;     // (+128 rows)
  int ldsB0 = 8192 + w * 512;
  int ldsB1 = 8192 + w * 512 + 4096;

  // --- read offsets (ushort idx): row*32 + swizzled 16B slot
  int rdswz = (lh ^ ((lr >> 1) & 3)) * 8;
  int aOff[8], bOff[4];
#pragma unroll
  for (int m = 0; m < 8; ++m) aOff[m] = (wr * 128 + m * 16 + lr) * 32 + rdswz;
#pragma unroll
  for (int n = 0; n < 4; ++n) bOff[n] = 8192 + (wc * 64 + n * 16 + lr) * 32 + rdswz;

  f32x4 acc[8][4];
#pragma unroll
  for (int m = 0; m < 8; ++m)
#pragma unroll
    for (int n = 0; n < 4; ++n) acc[m][n] = (f32x4){0.f, 0.f, 0.f, 0.f};

  // prologue: stage kt 0,1,2 into bufs 0,1,2 (12 loads in kt order)
  GLD16(aS0, &lds[ldsA0]);           GLD16(aS1, &lds[ldsA1]);
  GLD16(bS0, &lds[ldsB0]);           GLD16(bS1, &lds[ldsB1]);
  GLD16(aS0 + 32, &lds[16384 + ldsA0]); GLD16(aS1 + 32, &lds[16384 + ldsA1]);
  GLD16(bS0 + 32, &lds[16384 + ldsB0]); GLD16(bS1 + 32, &lds[16384 + ldsB1]);
  GLD16(aS0 + 64, &lds[32768 + ldsA0]); GLD16(aS1 + 64, &lds[32768 + ldsA1]);
  GLD16(bS0 + 64, &lds[32768 + ldsB0]); GLD16(bS1 + 64, &lds[32768 + ldsB1]);

  int t;
  for (t = 0; t < 61; ++t) K_ITER(8, true);
  K_ITER(8, false); ++t;  // t=61
  K_ITER(4, false); ++t;  // t=62
  K_ITER(0, false);       // t=63

  if constexpr (IS_G1) {
    const float scale = 0.02209708691207961f;  // 1/sqrt(2048)
    float g[4];
    int coln[4];
#pragma unroll
    for (int n = 0; n < 4; ++n) {
      int col = bcol * 256 + wc * 64 + n * 16 + lr;
      coln[n] = col;
      g[n] = scale / (1.0f + __expf(-span[col]));  // scale * sigmoid
    }
    unsigned short* Eb = (unsigned short*)outp + (size_t)b * S * S;
    float* Zb = Z + b * S;
#pragma unroll
    for (int m = 0; m < 8; ++m) {
      int rbase = brow * 256 + wr * 128 + m * 16 + lh * 4;
#pragma unroll
      for (int j = 0; j < 4; ++j) {
        int q = rbase + j;
        float rs = 0.f;
#pragma unroll
        for (int n = 0; n < 4; ++n) {
          float e = __expf(acc[m][n][j] * g[n]);
          Eb[(size_t)q * S + coln[n]] = f2bf(e);
          rs += e;
        }
        rs += __shfl_xor(rs, 1, 16);
        rs += __shfl_xor(rs, 2, 16);
        rs += __shfl_xor(rs, 4, 16);
        rs += __shfl_xor(rs, 8, 16);
        if (lr == 0) atomicAdd(&Zb[q], rs);
      }
    }
  } else {
    float* Ob = (float*)outp + (size_t)b * S * S;
    const float* Zb = Z + b * S;
#pragma unroll
    for (int m = 0; m < 8; ++m) {
      int rbase = brow * 256 + wr * 128 + m * 16 + lh * 4;
#pragma unroll
      for (int j = 0; j < 4; ++j) {
        int q = rbase + j;
        float zi = 1.0f / Zb[q];
#pragma unroll
        for (int n = 0; n < 4; ++n) {
          int col = bcol * 256 + wc * 64 + n * 16 + lr;
          Ob[(size_t)q * S + col] = acc[m][n][j] * zi;
        }
      }
    }
  }
}

extern "C" void kernel_launch(void* const* d_in, const int* in_sizes, int n_in,
                              void* d_out, int out_size, void* d_ws, size_t ws_size,
                              hipStream_t stream) {
  const float* Q = (const float*)d_in[0];
  const float* K = (const float*)d_in[1];
  const float* V = (const float*)d_in[2];
  const float* span = (const float*)d_in[3];
  char* ws = (char*)d_ws;

  const size_t TEN = (size_t)NB * SEQ * HID;
  unsigned short* Qb = (unsigned short*)(ws);
  unsigned short* Kb = (unsigned short*)(ws + TEN * 2);
  unsigned short* Vt = (unsigned short*)(ws + TEN * 4);
  unsigned short* E  = (unsigned short*)(ws + TEN * 6);
  float* Z = (float*)(ws + TEN * 8);

  hipMemsetAsync(Z, 0, (size_t)NB * SEQ * sizeof(float), stream);
  cvt2_kernel<<<8192, 256, 0, stream>>>(Q, K, Qb, Kb);
  tcvt_kernel<<<dim3(SEQ / 64, HID / 64, NB), 256, 0, stream>>>(V, Vt);
  gemm_kernel<true><<<256, 512, 0, stream>>>(Qb, Kb, E, Z, span);
  gemm_kernel<false><<<256, 512, 0, stream>>>(E, Vt, d_out, Z, nullptr);
}